// Round 1
// baseline (333.283 us; speedup 1.0000x reference)
//
#include <hip/hip_runtime.h>
#include <hip/hip_bf16.h>
#include <math.h>

// IDSCT2: out[b,u,v] = sum_{p,q} x[b,p,q] * S[u,p] * C[v,q]
//   S[u,p] = sin(pi*(2u+1)*p/(2M)), C[v,q] = cos(pi*(2v+1)*q/(2N))
// Implemented as two bf16-MFMA NT GEMMs per batch:
//   pass1: tT[b][v][p] = sum_q C[v][q] * xb[b][p][q]     (A=C, B=x[b])
//   pass2: out[b][u][v] = sum_p S[u][p] * tT[b][v][p]    (A=S, B=tT[b])

#define BM 128
#define BN 128
#define BK 32

typedef __bf16 bf16x8 __attribute__((ext_vector_type(8)));
typedef __bf16 bf16x4 __attribute__((ext_vector_type(4)));
typedef float floatx4 __attribute__((ext_vector_type(4)));

__device__ __forceinline__ void async_ld16(const void* g, void* l) {
    __builtin_amdgcn_global_load_lds(
        (__attribute__((address_space(1))) void*)(g),
        (__attribute__((address_space(3))) void*)(l), 16, 0, 0);
}

// Fill Cb[v*2048+q] = cos(pi*(2v+1)*q/4096), Sb[u*2048+p] = sin(same phase).
// Integer phase reduction mod 8192 keeps the fp32 trig argument < 2*pi (exact:
// (2v+1)*q <= 4095*2047 < 2^31).
__global__ void basis_kernel(__bf16* __restrict__ Cb, __bf16* __restrict__ Sb) {
    int idx = blockIdx.x * 256 + threadIdx.x;
    int v = idx >> 11;
    int q = idx & 2047;
    int phase = ((2 * v + 1) * q) & 8191;
    float ang = (float)phase * 7.669903939428206e-04f;  // pi/4096
    Cb[idx] = (__bf16)cosf(ang);
    Sb[idx] = (__bf16)sinf(ang);
}

// fp32 -> bf16, 4 elements/thread
__global__ void cvt_kernel(const float4* __restrict__ x, bf16x4* __restrict__ xb) {
    int i = blockIdx.x * 256 + threadIdx.x;
    float4 v = x[i];
    bf16x4 o;
    o[0] = (__bf16)v.x;
    o[1] = (__bf16)v.y;
    o[2] = (__bf16)v.z;
    o[3] = (__bf16)v.w;
    xb[i] = o;
}

// NT GEMM: D[i*Ndim+j] = sum_k A[i*K+k] * B[j*K+k], per blockIdx.z batch.
// 128x128 tile, BK=32, 256 threads = 4 waves (2x2, each wave 64x64 via 4x4
// mfma_f32_16x16x32_bf16 tiles). global_load_lds width-16 staging (LDS layout
// is forced: wave-uniform base + lane*16 -> row-major [row][BK], no padding).
template <typename OutT>
__global__ void __launch_bounds__(256) gemm_nt(
    const __bf16* __restrict__ A, const __bf16* __restrict__ B,
    OutT* __restrict__ D, int Ndim, int K,
    long batchA, long batchB, long batchD) {
    __shared__ __bf16 As[BM][BK];  // 8 KiB
    __shared__ __bf16 Bs[BN][BK];  // 8 KiB

    const int tid = threadIdx.x;
    const int lane = tid & 63;
    const int wave = tid >> 6;
    const int wr = wave >> 1;  // wave row in 2x2
    const int wc = wave & 1;   // wave col in 2x2

    A += batchA * blockIdx.z;
    B += batchB * blockIdx.z;
    D += batchD * blockIdx.z;

    const int row0 = blockIdx.y * BM;
    const int col0 = blockIdx.x * BN;

    // Staging: wave w covers LDS rows [w*32, w*32+32) in two 16-row slots.
    // Lane l -> row +l/4, 16B chunk (l&3) within the 64 B row.
    const int chunk = (lane & 3) * 8;               // element offset in row
    const int srow = wave * 32 + (lane >> 2);       // slot-0 row within tile
    const __bf16* a_src0 = A + (size_t)(row0 + srow) * K + chunk;
    const __bf16* a_src1 = a_src0 + (size_t)16 * K;
    const __bf16* b_src0 = B + (size_t)(col0 + srow) * K + chunk;
    const __bf16* b_src1 = b_src0 + (size_t)16 * K;
    __bf16* a_dst0 = &As[wave * 32][0];      // wave-uniform LDS bases
    __bf16* a_dst1 = &As[wave * 32 + 16][0];
    __bf16* b_dst0 = &Bs[wave * 32][0];
    __bf16* b_dst1 = &Bs[wave * 32 + 16][0];

    // MFMA fragment addressing (verified layouts):
    //   A-frag: lane holds A[m=lane&15][k=(lane>>4)*8 + j], j=0..7
    //   B-frag: lane holds B[n=lane&15][k=(lane>>4)*8 + j]  (NT: Bs rows = n)
    const int mrow = lane & 15;
    const int q8 = (lane >> 4) * 8;

    floatx4 acc[4][4] = {};

    for (int k0 = 0; k0 < K; k0 += BK) {
        async_ld16(a_src0 + k0, a_dst0);
        async_ld16(a_src1 + k0, a_dst1);
        async_ld16(b_src0 + k0, b_dst0);
        async_ld16(b_src1 + k0, b_dst1);
        __syncthreads();  // compiler emits s_waitcnt vmcnt(0) before barrier

        bf16x8 af[4], bfr[4];
#pragma unroll
        for (int t = 0; t < 4; ++t) {
            af[t]  = *(const bf16x8*)&As[wr * 64 + t * 16 + mrow][q8];
            bfr[t] = *(const bf16x8*)&Bs[wc * 64 + t * 16 + mrow][q8];
        }
#pragma unroll
        for (int i = 0; i < 4; ++i)
#pragma unroll
            for (int j = 0; j < 4; ++j)
                acc[i][j] = __builtin_amdgcn_mfma_f32_16x16x32_bf16(
                    af[i], bfr[j], acc[i][j], 0, 0, 0);
        __syncthreads();  // all waves done reading before next stage
    }

    // Epilogue: C/D layout col=lane&15, row=(lane>>4)*4+reg
    const int ecol = lane & 15;
    const int erow = (lane >> 4) * 4;
#pragma unroll
    for (int i = 0; i < 4; ++i)
#pragma unroll
        for (int j = 0; j < 4; ++j)
#pragma unroll
            for (int r = 0; r < 4; ++r) {
                int gi = row0 + wr * 64 + i * 16 + erow + r;
                int gj = col0 + wc * 64 + j * 16 + ecol;
                D[(size_t)gi * Ndim + gj] = (OutT)acc[i][j][r];
            }
}

extern "C" void kernel_launch(void* const* d_in, const int* in_sizes, int n_in,
                              void* d_out, int out_size, void* d_ws, size_t ws_size,
                              hipStream_t stream) {
    const float* x = (const float*)d_in[0];
    float* out = (float*)d_out;

    const int MN = 2048;
    const size_t mat = (size_t)MN * MN;  // 4M elems
    const size_t bmat = 4 * mat;         // 16M elems (B=4)

    // Workspace layout (80 MiB total):
    __bf16* Cb = (__bf16*)d_ws;   //  8 MiB
    __bf16* Sb = Cb + mat;        //  8 MiB
    __bf16* xb = Sb + mat;        // 32 MiB
    __bf16* tT = xb + bmat;       // 32 MiB

    basis_kernel<<<mat / 256, 256, 0, stream>>>(Cb, Sb);
    cvt_kernel<<<bmat / 4 / 256, 256, 0, stream>>>((const float4*)x, (bf16x4*)xb);

    dim3 grid(MN / BN, MN / BM, 4);
    // pass1: tT[b][v][p] = sum_q C[v][q] * xb[b][p][q]
    gemm_nt<__bf16><<<grid, 256, 0, stream>>>(Cb, xb, tT, MN, MN,
                                              0L, (long)mat, (long)mat);
    // pass2: out[b][u][v] = sum_p S[u][p] * tT[b][v][p]
    gemm_nt<float><<<grid, 256, 0, stream>>>(Sb, tT, out, MN, MN,
                                             0L, (long)mat, (long)mat);
}

// Round 2
// 285.970 us; speedup vs baseline: 1.1654x; 1.1654x over previous
//
#include <hip/hip_runtime.h>
#include <hip/hip_bf16.h>
#include <math.h>

// IDSCT2: out[b,u,v] = sum_{p,q} x[b,p,q] * S[u,p] * C[v,q]
//   S[u,p] = sin(pi*(2u+1)*p/(2M)), C[v,q] = cos(pi*(2v+1)*q/(2N))
// Two bf16-MFMA NT GEMMs per batch:
//   pass1: tT[b][v][p] = sum_q C[v][q] * xb[b][p][q]     (A=C, B=x[b])
//   pass2: out[b][u][v] = sum_p S[u][p] * tT[b][v][p]    (A=S, B=tT[b])
// R2: double-buffered LDS with loads issued AFTER the barrier (latency hidden
// behind compute); fast native trig in basis_kernel.

#define BM 128
#define BN 128
#define BK 32

typedef __bf16 bf16x8 __attribute__((ext_vector_type(8)));
typedef __bf16 bf16x4 __attribute__((ext_vector_type(4)));
typedef float floatx4 __attribute__((ext_vector_type(4)));

__device__ __forceinline__ void async_ld16(const void* g, void* l) {
    __builtin_amdgcn_global_load_lds(
        (__attribute__((address_space(1))) void*)(g),
        (__attribute__((address_space(3))) void*)(l), 16, 0, 0);
}

// Cb[v*2048+q] = cos(pi*(2v+1)*q/4096), Sb[u*2048+p] = sin(same phase).
// Integer phase mod 8192 keeps the fp32 trig arg < 2*pi; native v_sin/v_cos
// (via __sinf/__cosf) are accurate to far better than bf16 on [0, 2pi).
__global__ void basis_kernel(__bf16* __restrict__ Cb, __bf16* __restrict__ Sb) {
    int idx = blockIdx.x * 256 + threadIdx.x;
    int v = idx >> 11;
    int q = idx & 2047;
    int phase = ((2 * v + 1) * q) & 8191;
    float ang = (float)phase * 7.669903939428206e-04f;  // pi/4096
    Cb[idx] = (__bf16)__cosf(ang);
    Sb[idx] = (__bf16)__sinf(ang);
}

// fp32 -> bf16, 4 elements/thread
__global__ void cvt_kernel(const float4* __restrict__ x, bf16x4* __restrict__ xb) {
    int i = blockIdx.x * 256 + threadIdx.x;
    float4 v = x[i];
    bf16x4 o;
    o[0] = (__bf16)v.x;
    o[1] = (__bf16)v.y;
    o[2] = (__bf16)v.z;
    o[3] = (__bf16)v.w;
    xb[i] = o;
}

// NT GEMM: D[i*Ndim+j] = sum_k A[i*K+k] * B[j*K+k], per blockIdx.z batch.
// 128x128 tile, BK=32, 256 threads = 4 waves (2x2, each wave 64x64 via 4x4
// mfma_f32_16x16x32_bf16). Double-buffered LDS (2 x 16 KiB): stage(k+1) is
// issued after the barrier, so its vmem latency overlaps compute(k); the
// compiler's vmcnt(0)-before-s_barrier then finds the loads (mostly) landed.
template <typename OutT>
__global__ void __launch_bounds__(256) gemm_nt(
    const __bf16* __restrict__ A, const __bf16* __restrict__ B,
    OutT* __restrict__ D, int Ndim, int K,
    long batchA, long batchB, long batchD) {
    __shared__ __bf16 As[2][BM][BK];  // 2 x 8 KiB
    __shared__ __bf16 Bs[2][BN][BK];  // 2 x 8 KiB

    const int tid = threadIdx.x;
    const int lane = tid & 63;
    const int wave = tid >> 6;
    const int wr = wave >> 1;
    const int wc = wave & 1;

    A += batchA * blockIdx.z;
    B += batchB * blockIdx.z;
    D += batchD * blockIdx.z;

    const int row0 = blockIdx.y * BM;
    const int col0 = blockIdx.x * BN;

    // Staging: wave w covers tile rows [w*32, w*32+32) in two 16-row slots.
    // Lane l -> row + l/4, 16 B chunk (l&3). LDS dst is wave-uniform base +
    // lane*16 (hardware rule), giving row-major [row][BK] with no padding.
    const int chunk = (lane & 3) * 8;
    const int srow = wave * 32 + (lane >> 2);
    const __bf16* a_src0 = A + (size_t)(row0 + srow) * K + chunk;
    const __bf16* a_src1 = a_src0 + (size_t)16 * K;
    const __bf16* b_src0 = B + (size_t)(col0 + srow) * K + chunk;
    const __bf16* b_src1 = b_src0 + (size_t)16 * K;

    // MFMA fragment addressing (verified):
    //   A-frag: lane holds A[m=lane&15][k=(lane>>4)*8 + j], j=0..7
    //   B-frag: lane holds B[n=lane&15][k=(lane>>4)*8 + j]  (NT: Bs rows = n)
    const int mrow = lane & 15;
    const int q8 = (lane >> 4) * 8;

    floatx4 acc[4][4] = {};

    const int nIter = K / BK;

    // Prologue: stage k-tile 0 into buffer 0.
    {
        __bf16* ad0 = &As[0][wave * 32][0];
        __bf16* bd0 = &Bs[0][wave * 32][0];
        async_ld16(a_src0, ad0);
        async_ld16(a_src1, ad0 + 16 * BK);
        async_ld16(b_src0, bd0);
        async_ld16(b_src1, bd0 + 16 * BK);
    }

    for (int it = 0; it < nIter; ++it) {
        const int cur = it & 1;
        // Barrier: (a) compiler-inserted vmcnt(0) guarantees buf[cur] staged;
        // (b) all waves done ds_reading buf[cur^1] from iter it-1, so it is
        // safe to restage it below.
        __syncthreads();

        if (it + 1 < nIter) {
            const int nxt = cur ^ 1;
            const int k1 = (it + 1) * BK;
            __bf16* ad = &As[nxt][wave * 32][0];
            __bf16* bd = &Bs[nxt][wave * 32][0];
            async_ld16(a_src0 + k1, ad);
            async_ld16(a_src1 + k1, ad + 16 * BK);
            async_ld16(b_src0 + k1, bd);
            async_ld16(b_src1 + k1, bd + 16 * BK);
        }

        bf16x8 af[4], bfr[4];
#pragma unroll
        for (int t = 0; t < 4; ++t) {
            af[t]  = *(const bf16x8*)&As[cur][wr * 64 + t * 16 + mrow][q8];
            bfr[t] = *(const bf16x8*)&Bs[cur][wc * 64 + t * 16 + mrow][q8];
        }
#pragma unroll
        for (int i = 0; i < 4; ++i)
#pragma unroll
            for (int j = 0; j < 4; ++j)
                acc[i][j] = __builtin_amdgcn_mfma_f32_16x16x32_bf16(
                    af[i], bfr[j], acc[i][j], 0, 0, 0);
    }

    // Epilogue: C/D layout col=lane&15, row=(lane>>4)*4+reg
    const int ecol = lane & 15;
    const int erow = (lane >> 4) * 4;
#pragma unroll
    for (int i = 0; i < 4; ++i)
#pragma unroll
        for (int j = 0; j < 4; ++j)
#pragma unroll
            for (int r = 0; r < 4; ++r) {
                int gi = row0 + wr * 64 + i * 16 + erow + r;
                int gj = col0 + wc * 64 + j * 16 + ecol;
                D[(size_t)gi * Ndim + gj] = (OutT)acc[i][j][r];
            }
}

extern "C" void kernel_launch(void* const* d_in, const int* in_sizes, int n_in,
                              void* d_out, int out_size, void* d_ws, size_t ws_size,
                              hipStream_t stream) {
    const float* x = (const float*)d_in[0];
    float* out = (float*)d_out;

    const int MN = 2048;
    const size_t mat = (size_t)MN * MN;  // 4M elems
    const size_t bmat = 4 * mat;         // 16M elems (B=4)

    // Workspace layout (80 MiB total):
    __bf16* Cb = (__bf16*)d_ws;   //  8 MiB
    __bf16* Sb = Cb + mat;        //  8 MiB
    __bf16* xb = Sb + mat;        // 32 MiB
    __bf16* tT = xb + bmat;       // 32 MiB

    basis_kernel<<<mat / 256, 256, 0, stream>>>(Cb, Sb);
    cvt_kernel<<<bmat / 4 / 256, 256, 0, stream>>>((const float4*)x, (bf16x4*)xb);

    dim3 grid(MN / BN, MN / BM, 4);
    // pass1: tT[b][v][p] = sum_q C[v][q] * xb[b][p][q]
    gemm_nt<__bf16><<<grid, 256, 0, stream>>>(Cb, xb, tT, MN, MN,
                                              0L, (long)mat, (long)mat);
    // pass2: out[b][u][v] = sum_p S[u][p] * tT[b][v][p]
    gemm_nt<float><<<grid, 256, 0, stream>>>(Sb, tT, out, MN, MN,
                                             0L, (long)mat, (long)mat);
}